// Round 5
// baseline (694.398 us; speedup 1.0000x reference)
//
#include <hip/hip_runtime.h>
#include <hip/hip_bf16.h>

#define N 8192
#define C 256
#define NCLS 1000

typedef __bf16 bf16x8 __attribute__((ext_vector_type(8)));
typedef float floatx4 __attribute__((ext_vector_type(4)));

__device__ __forceinline__ void gload_lds16(const void* g, void* l) {
    __builtin_amdgcn_global_load_lds(
        (const __attribute__((address_space(1))) void*)g,
        (__attribute__((address_space(3))) void*)l, 16, 0, 0);
}

__device__ __forceinline__ unsigned short f2bf(float x) {
    union { float f; unsigned int u; } a; a.f = x;
    unsigned int u = a.u;
    unsigned int r = (u + 0x7fffu + ((u >> 16) & 1u)) >> 16;  // RNE
    return (unsigned short)r;
}

// --- 1. row L2-normalize + cast to bf16 ------------------------------------
__global__ __launch_bounds__(256) void k_norm(const float* __restrict__ f,
                                              unsigned short* __restrict__ fnb) {
    int wid = threadIdx.x >> 6, lane = threadIdx.x & 63;
    int row = blockIdx.x * 4 + wid;
    const float4* fr = (const float4*)(f + (size_t)row * C);
    float4 v = fr[lane];
    float ss = v.x * v.x + v.y * v.y + v.z * v.z + v.w * v.w;
    #pragma unroll
    for (int m = 1; m < 64; m <<= 1) ss += __shfl_xor(ss, m, 64);
    float scale = 1.0f / fmaxf(sqrtf(ss), 1e-8f);
    ushort4 o;
    o.x = f2bf(v.x * scale); o.y = f2bf(v.y * scale);
    o.z = f2bf(v.z * scale); o.w = f2bf(v.w * scale);
    ((ushort4*)(fnb + (size_t)row * C))[lane] = o;
}

// --- 2. class histogram (single block) -------------------------------------
__global__ __launch_bounds__(1024) void k_hist(const int* __restrict__ lab,
                                               int* __restrict__ cnt) {
    __shared__ int bins[NCLS];
    for (int i = threadIdx.x; i < NCLS; i += 1024) bins[i] = 0;
    __syncthreads();
    for (int i = threadIdx.x; i < N; i += 1024) atomicAdd(&bins[lab[i]], 1);
    __syncthreads();
    for (int i = threadIdx.x; i < NCLS; i += 1024) cnt[i] = bins[i];
}

// --- 2b. perfect_logit: pure streaming label-compare writer ----------------
__global__ __launch_bounds__(256) void k_perfect(const int* __restrict__ lab,
                                                 float* __restrict__ perfect) {
    __shared__ int labs[N];   // 32 KiB
    const int t = threadIdx.x;
    #pragma unroll
    for (int p = 0; p < N / (256 * 4); ++p) {
        int idx = (p * 256 + t) * 4;
        int4 v = *(const int4*)(lab + idx);
        *(int4*)&labs[idx] = v;
    }
    __syncthreads();
    int row0 = blockIdx.x * 4;
    #pragma unroll
    for (int rr = 0; rr < 4; ++rr) {
        int row = row0 + rr;
        int lr = labs[row];
        float* dst = perfect + (size_t)row * N;
        #pragma unroll
        for (int p = 0; p < 8; ++p) {
            int c = (p * 256 + t) * 4;
            floatx4 pv;
            pv[0] = (labs[c + 0] == lr) ? 1.0f : -1.0f;
            pv[1] = (labs[c + 1] == lr) ? 1.0f : -1.0f;
            pv[2] = (labs[c + 2] == lr) ? 1.0f : -1.0f;
            pv[3] = (labs[c + 3] == lr) ? 1.0f : -1.0f;
            *(floatx4*)(dst + c) = pv;
        }
    }
}

// --- 3. fused symmetric GEMM: upper-triangle, dual accumulators ------------
// acc  = mfma(a,b): thread holds 4 consecutive ROWS / fixed col  -> mirror store
// accT = mfma(b,a): thread holds 4 consecutive COLS / fixed row  -> row store
// Every logits store is a float4; no barriers after the K-loop.
__global__ __launch_bounds__(256) void k_gemm(
    const unsigned short* __restrict__ fnb, const int* __restrict__ lab,
    float* __restrict__ logits,
    float* __restrict__ Ssum, float* __restrict__ Psum) {
    const int bx = blockIdx.x, by = blockIdx.y;
    if (bx < by) return;                 // upper triangle only (colBase >= rowBase)
    const bool diag = (bx == by);

    __shared__ __align__(16) unsigned short As[128 * 32];
    __shared__ __align__(16) unsigned short Bs[128 * 32];
    __shared__ __align__(16) int Lr[128];
    __shared__ __align__(16) int Lc[128];

    const int t = threadIdx.x;
    const int wid = t >> 6, lane = t & 63;
    const int waveM = wid >> 1, waveN = wid & 1;
    const int quad = lane >> 4, l15 = lane & 15;
    const int rowBase = by * 128;
    const int colBase = bx * 128;

    if (t < 128) Lr[t] = lab[rowBase + t];
    else         Lc[t - 128] = lab[colBase + (t - 128)];

    floatx4 acc[4][4] = {};
    floatx4 accT[4][4] = {};

    // staging: thread t loads 16B = 8 bf16 ; row = wid*16 + lane/4
    const int srow = wid * 16 + (lane >> 2);
    const int scol = (lane & 3) * 8;
    const unsigned short* gA = fnb + (size_t)(rowBase + srow) * C + scol;
    const unsigned short* gB = fnb + (size_t)(colBase + srow) * C + scol;
    char* asb = (char*)As + wid * 1024;
    char* bsb = (char*)Bs + wid * 1024;

    for (int kb = 0; kb < C; kb += 32) {
        __syncthreads();
        gload_lds16(gA + kb,           asb);
        gload_lds16(gA + kb + 64 * C,  asb + 4096);
        gload_lds16(gB + kb,           bsb);
        gload_lds16(gB + kb + 64 * C,  bsb + 4096);
        __syncthreads();
        bf16x8 a[4], b[4];
        #pragma unroll
        for (int i = 0; i < 4; ++i) {
            a[i] = *(const bf16x8*)&As[(waveM * 64 + i * 16 + l15) * 32 + quad * 8];
            b[i] = *(const bf16x8*)&Bs[(waveN * 64 + i * 16 + l15) * 32 + quad * 8];
        }
        #pragma unroll
        for (int i = 0; i < 4; ++i)
            #pragma unroll
            for (int j = 0; j < 4; ++j) {
                acc[i][j]  = __builtin_amdgcn_mfma_f32_16x16x32_bf16(a[i], b[j], acc[i][j], 0, 0, 0);
                accT[j][i] = __builtin_amdgcn_mfma_f32_16x16x32_bf16(b[j], a[i], accT[j][i], 0, 0, 0);
            }
    }

    const float invT = 10.0f;

    // ---- row-side stores from accT: 16 float4, fully coalesced -------------
    #pragma unroll
    for (int i = 0; i < 4; ++i) {
        int row = rowBase + waveM * 64 + i * 16 + l15;
        float* rp = logits + (size_t)row * N + colBase + waveN * 64 + quad * 4;
        #pragma unroll
        for (int j = 0; j < 4; ++j) {
            floatx4 w;
            w[0] = accT[j][i][0] * invT; w[1] = accT[j][i][1] * invT;
            w[2] = accT[j][i][2] * invT; w[3] = accT[j][i][3] * invT;
            *(floatx4*)(rp + j * 16) = w;
        }
    }

    // ---- mirror stores from acc: 16 float4, fully coalesced ----------------
    if (!diag) {
        #pragma unroll
        for (int j = 0; j < 4; ++j) {
            int mrow = colBase + waveN * 64 + j * 16 + l15;
            float* mp = logits + (size_t)mrow * N + rowBase + waveM * 64 + quad * 4;
            #pragma unroll
            for (int i = 0; i < 4; ++i) {
                floatx4 w;
                w[0] = acc[i][j][0] * invT; w[1] = acc[i][j][1] * invT;
                w[2] = acc[i][j][2] * invT; w[3] = acc[i][j][3] * invT;
                *(floatx4*)(mp + i * 16) = w;
            }
        }
    }

    // ---- S/P row and col partials from acc (stores drain underneath) -------
    float colS[4] = {0.f, 0.f, 0.f, 0.f};
    float colP[4] = {0.f, 0.f, 0.f, 0.f};

    #pragma unroll
    for (int i = 0; i < 4; ++i) {
        #pragma unroll
        for (int r = 0; r < 4; ++r) {
            int lrow = waveM * 64 + i * 16 + quad * 4 + r;
            int row = rowBase + lrow;
            int labr = Lr[lrow];
            float eS = 0.f, pS = 0.f;
            #pragma unroll
            for (int j = 0; j < 4; ++j) {
                int lcol = waveN * 64 + j * 16 + l15;
                int col = colBase + lcol;
                float v = acc[i][j][r] * invT;
                bool same = (labr == Lc[lcol]);
                if (!diag || row != col) {
                    float e = __expf(v);
                    eS += e;
                    if (same) pS += v;
                    if (!diag) {
                        colS[j] += e;
                        if (same) colP[j] += v;
                    }
                }
            }
            #pragma unroll
            for (int m = 1; m < 16; m <<= 1) {
                eS += __shfl_xor(eS, m, 64);
                pS += __shfl_xor(pS, m, 64);
            }
            if (l15 == 0) {
                atomicAdd(&Ssum[row], eS);
                if (pS != 0.0f) atomicAdd(&Psum[row], pS);
            }
        }
    }

    if (!diag) {
        #pragma unroll
        for (int j = 0; j < 4; ++j) {
            float cs = colS[j], cp = colP[j];
            cs += __shfl_xor(cs, 16, 64); cs += __shfl_xor(cs, 32, 64);
            cp += __shfl_xor(cp, 16, 64); cp += __shfl_xor(cp, 32, 64);
            if (quad == 0) {
                int col = colBase + waveN * 64 + j * 16 + l15;
                atomicAdd(&Ssum[col], cs);
                if (cp != 0.0f) atomicAdd(&Psum[col], cp);
            }
        }
    }
}

// --- 4. final loss reduction (single block) --------------------------------
__global__ __launch_bounds__(1024) void k_loss(
    const float* __restrict__ S, const float* __restrict__ P,
    const int* __restrict__ lab, const int* __restrict__ cnt,
    float* __restrict__ out) {
    float sum = 0.f;
    for (int i = threadIdx.x; i < N; i += 1024) {
        float Ki = (float)(cnt[lab[i]] - 1);
        float term = (P[i] - Ki * logf(S[i])) / (Ki + 1e-6f);
        sum += term;
    }
    #pragma unroll
    for (int m = 1; m < 64; m <<= 1) sum += __shfl_xor(sum, m, 64);
    __shared__ float wsum[16];
    int wid = threadIdx.x >> 6, lane = threadIdx.x & 63;
    if (lane == 0) wsum[wid] = sum;
    __syncthreads();
    if (threadIdx.x == 0) {
        float tot = 0.f;
        #pragma unroll
        for (int i = 0; i < 16; ++i) tot += wsum[i];
        out[0] = -tot / (float)N;
    }
}

extern "C" void kernel_launch(void* const* d_in, const int* in_sizes, int n_in,
                              void* d_out, int out_size, void* d_ws, size_t ws_size,
                              hipStream_t stream) {
    const float* f = (const float*)d_in[0];
    const int* lab = (const int*)d_in[1];
    float* out = (float*)d_out;
    float* logits = out + 1;
    float* perfect = out + 1 + (size_t)N * N;

    unsigned short* fnb = (unsigned short*)d_ws;                 // 4 MiB
    float* Ssum = (float*)((char*)d_ws + (size_t)N * C * 2);     // 32 KiB
    float* Psum = Ssum + N;                                      // 32 KiB
    int* cnt = (int*)(Psum + N);                                 // 4 KB

    hipMemsetAsync(Ssum, 0, 2 * N * sizeof(float), stream);
    k_perfect<<<N / 4, 256, 0, stream>>>(lab, perfect);
    k_norm<<<N / 4, 256, 0, stream>>>(f, fnb);
    k_hist<<<1, 1024, 0, stream>>>(lab, cnt);
    k_gemm<<<dim3(64, 64), 256, 0, stream>>>(fnb, lab, logits, Ssum, Psum);
    k_loss<<<1, 1024, 0, stream>>>(Ssum, Psum, lab, cnt, out);
}

// Round 6
// 631.959 us; speedup vs baseline: 1.0988x; 1.0988x over previous
//
#include <hip/hip_runtime.h>
#include <hip/hip_bf16.h>

#define N 8192
#define C 256
#define NCLS 1000

typedef __bf16 bf16x8 __attribute__((ext_vector_type(8)));
typedef float floatx4 __attribute__((ext_vector_type(4)));

__device__ __forceinline__ void gload_lds16(const void* g, void* l) {
    __builtin_amdgcn_global_load_lds(
        (const __attribute__((address_space(1))) void*)g,
        (__attribute__((address_space(3))) void*)l, 16, 0, 0);
}

__device__ __forceinline__ unsigned short f2bf(float x) {
    union { float f; unsigned int u; } a; a.f = x;
    unsigned int u = a.u;
    unsigned int r = (u + 0x7fffu + ((u >> 16) & 1u)) >> 16;  // RNE
    return (unsigned short)r;
}

// --- 1. row L2-normalize + cast to bf16 ------------------------------------
__global__ __launch_bounds__(256) void k_norm(const float* __restrict__ f,
                                              unsigned short* __restrict__ fnb) {
    int wid = threadIdx.x >> 6, lane = threadIdx.x & 63;
    int row = blockIdx.x * 4 + wid;
    const float4* fr = (const float4*)(f + (size_t)row * C);
    float4 v = fr[lane];
    float ss = v.x * v.x + v.y * v.y + v.z * v.z + v.w * v.w;
    #pragma unroll
    for (int m = 1; m < 64; m <<= 1) ss += __shfl_xor(ss, m, 64);
    float scale = 1.0f / fmaxf(sqrtf(ss), 1e-8f);
    ushort4 o;
    o.x = f2bf(v.x * scale); o.y = f2bf(v.y * scale);
    o.z = f2bf(v.z * scale); o.w = f2bf(v.w * scale);
    ((ushort4*)(fnb + (size_t)row * C))[lane] = o;
}

// --- 2. class histogram (single block) -------------------------------------
__global__ __launch_bounds__(1024) void k_hist(const int* __restrict__ lab,
                                               int* __restrict__ cnt) {
    __shared__ int bins[NCLS];
    for (int i = threadIdx.x; i < NCLS; i += 1024) bins[i] = 0;
    __syncthreads();
    for (int i = threadIdx.x; i < N; i += 1024) atomicAdd(&bins[lab[i]], 1);
    __syncthreads();
    for (int i = threadIdx.x; i < NCLS; i += 1024) cnt[i] = bins[i];
}

// --- 2b. perfect_logit: streaming label-compare writer ---------------------
// 8 rows/block; labels read once per pass as int4, compared to 8 row-labels.
__global__ __launch_bounds__(256) void k_perfect(const int* __restrict__ lab,
                                                 float* __restrict__ perfect) {
    __shared__ __align__(16) int labs[N];   // 32 KiB
    const int t = threadIdx.x;
    #pragma unroll
    for (int p = 0; p < 8; ++p) {
        int idx = (p * 256 + t) * 4;
        *(int4*)&labs[idx] = *(const int4*)(lab + idx);
    }
    __syncthreads();
    const int row0 = blockIdx.x * 8;
    int lr[8];
    #pragma unroll
    for (int rr = 0; rr < 8; ++rr) lr[rr] = labs[row0 + rr];
    #pragma unroll
    for (int p = 0; p < 8; ++p) {
        int c = (p * 256 + t) * 4;
        int4 lv = *(const int4*)&labs[c];
        #pragma unroll
        for (int rr = 0; rr < 8; ++rr) {
            floatx4 pv;
            pv[0] = (lv.x == lr[rr]) ? 1.0f : -1.0f;
            pv[1] = (lv.y == lr[rr]) ? 1.0f : -1.0f;
            pv[2] = (lv.z == lr[rr]) ? 1.0f : -1.0f;
            pv[3] = (lv.w == lr[rr]) ? 1.0f : -1.0f;
            *(floatx4*)(perfect + (size_t)(row0 + rr) * N + c) = pv;
        }
    }
}

// --- 3. fused symmetric GEMM: triangular grid, double-buffered K-loop ------
// One barrier per K-step; next tile's global_load_lds issued BEFORE compute
// so HBM/L2 latency hides under ds_read+MFMA (T3-minimum 2-phase schedule).
__global__ __launch_bounds__(256) void k_gemm(
    const unsigned short* __restrict__ fnb, const int* __restrict__ lab,
    float* __restrict__ logits,
    float* __restrict__ Ssum, float* __restrict__ Psum) {
    // triangular decode: block k -> (bx,by), bx >= by
    int k = blockIdx.x;
    int r = (int)((sqrtf(8.0f * (float)k + 1.0f) - 1.0f) * 0.5f);
    while ((r + 1) * (r + 2) / 2 <= k) ++r;
    while (r * (r + 1) / 2 > k) --r;
    const int bx = r, by = k - r * (r + 1) / 2;
    const bool diag = (bx == by);

    // smem: [A0 8K][B0 8K][A1 8K][B1 8K]; transpose buffer T overlays front.
    __shared__ __align__(16) char smem[32768];
    float* T = (float*)smem;             // [32][132] f32 = 16896 B
    __shared__ __align__(16) int Lr[128];
    __shared__ __align__(16) int Lc[128];

    const int t = threadIdx.x;
    const int wid = t >> 6, lane = t & 63;
    const int waveM = wid >> 1, waveN = wid & 1;
    const int quad = lane >> 4, l15 = lane & 15;
    const int rowBase = by * 128;
    const int colBase = bx * 128;

    if (t < 128) Lr[t] = lab[rowBase + t];
    else         Lc[t - 128] = lab[colBase + (t - 128)];

    floatx4 acc[4][4] = {};

    // staging: thread t loads 16B = 8 bf16 ; row = wid*16 + lane/4
    const int srow = wid * 16 + (lane >> 2);
    const int scol = (lane & 3) * 8;
    const unsigned short* gA = fnb + (size_t)(rowBase + srow) * C + scol;
    const unsigned short* gB = fnb + (size_t)(colBase + srow) * C + scol;

    #define STAGE(buf, kb) do {                                   \
        char* asb = smem + (buf) * 16384 + wid * 1024;            \
        char* bsb = asb + 8192;                                   \
        gload_lds16(gA + (kb),          asb);                     \
        gload_lds16(gA + (kb) + 64 * C, asb + 4096);              \
        gload_lds16(gB + (kb),          bsb);                     \
        gload_lds16(gB + (kb) + 64 * C, bsb + 4096);              \
    } while (0)

    STAGE(0, 0);
    __syncthreads();                     // drain stage-0, all waves ready
    #pragma unroll
    for (int it = 0; it < 8; ++it) {
        const int cur = it & 1;
        if (it < 7) STAGE(cur ^ 1, (it + 1) * 32);   // prefetch next tile
        const unsigned short* Ab = (const unsigned short*)(smem + cur * 16384);
        const unsigned short* Bb = Ab + 4096;
        bf16x8 a[4], b[4];
        #pragma unroll
        for (int i = 0; i < 4; ++i) {
            a[i] = *(const bf16x8*)&Ab[(waveM * 64 + i * 16 + l15) * 32 + quad * 8];
            b[i] = *(const bf16x8*)&Bb[(waveN * 64 + i * 16 + l15) * 32 + quad * 8];
        }
        #pragma unroll
        for (int i = 0; i < 4; ++i)
            #pragma unroll
            for (int j = 0; j < 4; ++j)
                acc[i][j] = __builtin_amdgcn_mfma_f32_16x16x32_bf16(a[i], b[j], acc[i][j], 0, 0, 0);
        __syncthreads();                 // drains vmcnt (prefetch) + lgkm; guards buffer swap
    }
    #undef STAGE

    // ---- row-side epilogue: logits stores + S/P row and col partials ----
    const float invT = 10.0f;
    float colS[4] = {0.f, 0.f, 0.f, 0.f};
    float colP[4] = {0.f, 0.f, 0.f, 0.f};

    #pragma unroll
    for (int i = 0; i < 4; ++i) {
        #pragma unroll
        for (int r2 = 0; r2 < 4; ++r2) {
            int lrow = waveM * 64 + i * 16 + quad * 4 + r2;
            int row = rowBase + lrow;
            int labr = Lr[lrow];
            float eS = 0.f, pS = 0.f;
            #pragma unroll
            for (int j = 0; j < 4; ++j) {
                int lcol = waveN * 64 + j * 16 + l15;
                int col = colBase + lcol;
                float v = acc[i][j][r2] * invT;
                size_t off = (size_t)row * N + col;
                bool same = (labr == Lc[lcol]);
                logits[off] = v;
                if (!diag || row != col) {
                    float e = __expf(v);
                    eS += e;
                    if (same) pS += v;
                    if (!diag) {
                        colS[j] += e;
                        if (same) colP[j] += v;
                    }
                }
            }
            #pragma unroll
            for (int m = 1; m < 16; m <<= 1) {
                eS += __shfl_xor(eS, m, 64);
                pS += __shfl_xor(pS, m, 64);
            }
            if (l15 == 0) {
                atomicAdd(&Ssum[row], eS);
                if (pS != 0.0f) atomicAdd(&Psum[row], pS);
            }
        }
    }

    if (!diag) {
        // column-side S/P: reduce over the 4 quads of this wave's 64 rows
        #pragma unroll
        for (int j = 0; j < 4; ++j) {
            float cs = colS[j], cp = colP[j];
            cs += __shfl_xor(cs, 16, 64); cs += __shfl_xor(cs, 32, 64);
            cp += __shfl_xor(cp, 16, 64); cp += __shfl_xor(cp, 32, 64);
            if (quad == 0) {
                int col = colBase + waveN * 64 + j * 16 + l15;
                atomicAdd(&Ssum[col], cs);
                if (cp != 0.0f) atomicAdd(&Psum[col], cp);
            }
        }

        // ---- mirror tile via LDS transpose: 4 chunks of 32 cols ----
        #pragma unroll
        for (int c = 0; c < 4; ++c) {
            __syncthreads();             // previous chunk reads (or K-loop) done
            if (waveN == (c >> 1)) {
                #pragma unroll
                for (int jj = 0; jj < 2; ++jj) {
                    int j = (c & 1) * 2 + jj;
                    int tr = jj * 16 + l15;          // row within chunk = lcol - c*32
                    #pragma unroll
                    for (int i = 0; i < 4; ++i) {
                        floatx4 w;
                        w[0] = acc[i][j][0] * invT; w[1] = acc[i][j][1] * invT;
                        w[2] = acc[i][j][2] * invT; w[3] = acc[i][j][3] * invT;
                        *(floatx4*)&T[tr * 132 + waveM * 64 + i * 16 + quad * 4] = w;
                    }
                }
            }
            __syncthreads();
            // cooperative coalesced store: 32 rows x 128 cols
            #pragma unroll
            for (int pass = 0; pass < 4; ++pass) {
                int rr = pass * 8 + (t >> 5);
                int cv = (t & 31) * 4;
                floatx4 lv = *(const floatx4*)&T[rr * 132 + cv];
                size_t off = (size_t)(colBase + c * 32 + rr) * N + rowBase + cv;
                *(floatx4*)(logits + off) = lv;
            }
        }
    }
}

// --- 4. final loss reduction (single block) --------------------------------
__global__ __launch_bounds__(1024) void k_loss(
    const float* __restrict__ S, const float* __restrict__ P,
    const int* __restrict__ lab, const int* __restrict__ cnt,
    float* __restrict__ out) {
    float sum = 0.f;
    for (int i = threadIdx.x; i < N; i += 1024) {
        float Ki = (float)(cnt[lab[i]] - 1);
        float term = (P[i] - Ki * logf(S[i])) / (Ki + 1e-6f);
        sum += term;
    }
    #pragma unroll
    for (int m = 1; m < 64; m <<= 1) sum += __shfl_xor(sum, m, 64);
    __shared__ float wsum[16];
    int wid = threadIdx.x >> 6, lane = threadIdx.x & 63;
    if (lane == 0) wsum[wid] = sum;
    __syncthreads();
    if (threadIdx.x == 0) {
        float tot = 0.f;
        #pragma unroll
        for (int i = 0; i < 16; ++i) tot += wsum[i];
        out[0] = -tot / (float)N;
    }
}

extern "C" void kernel_launch(void* const* d_in, const int* in_sizes, int n_in,
                              void* d_out, int out_size, void* d_ws, size_t ws_size,
                              hipStream_t stream) {
    const float* f = (const float*)d_in[0];
    const int* lab = (const int*)d_in[1];
    float* out = (float*)d_out;
    float* logits = out + 1;
    float* perfect = out + 1 + (size_t)N * N;

    unsigned short* fnb = (unsigned short*)d_ws;                 // 4 MiB
    float* Ssum = (float*)((char*)d_ws + (size_t)N * C * 2);     // 32 KiB
    float* Psum = Ssum + N;                                      // 32 KiB
    int* cnt = (int*)(Psum + N);                                 // 4 KB

    hipMemsetAsync(Ssum, 0, 2 * N * sizeof(float), stream);
    k_perfect<<<N / 8, 256, 0, stream>>>(lab, perfect);
    k_norm<<<N / 4, 256, 0, stream>>>(f, fnb);
    k_hist<<<1, 1024, 0, stream>>>(lab, cnt);
    k_gemm<<<2080, 256, 0, stream>>>(fnb, lab, logits, Ssum, Psum);
    k_loss<<<1, 1024, 0, stream>>>(Ssum, Psum, lab, cnt, out);
}